// Round 10
// baseline (817.537 us; speedup 1.0000x reference)
//
#include <hip/hip_runtime.h>
#include <cmath>

#define NROWS 65536
#define EDIM  1024
#define KST   4

// ---- pre-kernel: transpose W_inv (4,1024,5) -> WiT (4,5,1024) in d_ws ----
__global__ __launch_bounds__(256) void winv_transpose(const float* __restrict__ W_inv,
                                                      float* __restrict__ WiT) {
    const int t = blockIdx.x * 256 + threadIdx.x;   // 4096 threads total
    const int i = t >> 10;                          // stage
    const int e = t & 1023;
    const float* src = W_inv + (size_t)i * 5120 + (size_t)e * 5;
    const float w0 = src[0], w1 = src[1], w2 = src[2], w3 = src[3], w4 = src[4];
    float* dst = WiT + (size_t)i * 5120 + e;
    dst[0]    = w0;
    dst[1024] = w1;
    dst[2048] = w2;
    dst[3072] = w3;
    dst[4096] = w4;
}

// R9 (367us kernel, VGPR=104, no spills) + occupancy push:
//  - LDS holds ONLY WiT (20480 B; was 45.5 KB) -> LDS allows 8 blocks/CU,
//    occupancy now VGPR-capped at ~4 waves/SIMD (~16 waves/CU, 2.3x R9).
//  - Wp read directly from global in proj (same 20 KB lines for every wave
//    on the CU -> L1/L2-hot; identical values & FMA order).
//  - b_inv from global, issued at stage top, consumed at stage end.
//  - barrier A -> ds_write WiT -> proj (no LDS deps) -> barrier B -> inverse:
//    staging writes complete UNDER proj, so barrier B drains nothing.
// Numerics bit-identical to the R1/R9 passing sequences.
__global__ __launch_bounds__(256, 2) void rvq_fused(
    const float* __restrict__ h_in,    // (N,1024)
    const float* __restrict__ W_proj,  // (4,5,1024)
    const float* __restrict__ b_proj,  // (4,5)
    const float* __restrict__ WiT,     // (4,5,1024) transposed W_inv
    const float* __restrict__ b_inv,   // (4,1024)
    const float* __restrict__ temp,    // (1)
    const float* __restrict__ u,       // (4,N,5,8)
    const float* __restrict__ p,       // (N)
    float* __restrict__ out_q,         // (N,1024)
    float* __restrict__ out_code,      // (N,20)
    float* __restrict__ out_loss,      // (1)
    float shift012, float shift3)
{
    __shared__ float sWi[5120];   // 20480 B: WiT[d][e] for current stage
    __shared__ float sLoss[4];

    const int tid  = threadIdx.x;
    const int lane = tid & 63;
    const int wib  = tid >> 6;                  // 0..3
    const int wid  = blockIdx.x * 4 + wib;
    const int row0 = wid * 2;                   // 2 rows per wave

    // ---- lane-role constants (d,c) grid; lanes 40..63 duplicate d=4 ----
    int dl = lane >> 3; if (dl > 4) dl = 4;
    const int   cl     = lane & 7;
    const float stepf  = (float)(cl - 4);
    const bool  valid  = (dl < 3) || (dl == 3 && cl >= 1 && cl <= 6)
                                  || (dl == 4 && cl >= 2 && cl <= 6);
    const float shiftd = (dl < 3) ? shift012 : ((dl == 3) ? shift3 : 0.0f);
    const float halfld = (dl < 3) ? 3.4965f : ((dl == 3) ? 2.4975f : 1.998f);
    const float offd   = (dl == 4) ? 0.0f : 0.5f;
    const float invhwd = (dl < 3) ? 0.25f : ((dl == 3) ? (1.0f/3.0f) : 0.5f);
    const int   ulane  = (lane < 40) ? lane : 39;

    const float tval = temp[0];
    const float te = fmaxf(tval * tval, 1e-8f);       // temp_eff
    const float inv_te  = 1.0f / te;                  // == alpha
    const float alpham1 = inv_te - 1.0f;

    // ---- preload ALL stages' gumbel uniforms (8 regs) + rows + p ----
    float uu[KST][2];
    #pragma unroll
    for (int i = 0; i < KST; ++i)
        #pragma unroll
        for (int rr = 0; rr < 2; ++rr)
            uu[i][rr] = u[(size_t)i * 2621440 + (size_t)(row0 + rr) * 40 + ulane];

    float4 r4[2][4];
    float  p_r[2];
    float  ss[2];
    #pragma unroll
    for (int rr = 0; rr < 2; ++rr) {
        const float4* src = (const float4*)(h_in + (size_t)(row0 + rr) * EDIM);
        #pragma unroll
        for (int j = 0; j < 4; ++j) r4[rr][j] = src[lane + 64 * j];
        p_r[rr] = p[row0 + rr];
        float s = 0.f;
        #pragma unroll
        for (int j = 0; j < 4; ++j) {
            s = fmaf(r4[rr][j].x, r4[rr][j].x, s);
            s = fmaf(r4[rr][j].y, r4[rr][j].y, s);
            s = fmaf(r4[rr][j].z, r4[rr][j].z, s);
            s = fmaf(r4[rr][j].w, r4[rr][j].w, s);
        }
        ss[rr] = (p_r[rr] <= 0.0f) ? s : 0.0f;   // p==0 edge: q_mix=0 -> ||h_in||
    }

    for (int i = 0; i < KST; ++i) {
        // ---- issue WiT stage loads + b_inv loads (latency hides under
        //      barrier + proj; ds_write waits only on wreg) ----
        const float4* gw = (const float4*)(WiT + (size_t)i * 5120);
        float4 wreg[5];
        #pragma unroll
        for (int k = 0; k < 5; ++k) wreg[k] = gw[tid + k * 256];
        const float4* bvp = (const float4*)(b_inv + (size_t)i * EDIM);
        float4 bv[4];
        #pragma unroll
        for (int j = 0; j < 4; ++j) bv[j] = bvp[lane + 64 * j];

        __syncthreads();   // A: previous stage's sWi readers are done
        {
            float4* sw = (float4*)sWi;
            #pragma unroll
            for (int k = 0; k < 5; ++k) sw[tid + k * 256] = wreg[k];
        }

        // ---- proj (NO LDS deps — runs while ds_writes complete):
        //      h[d] = sum_e Wp[d][e]*r[e]; butterfly per d (identical order) ----
        float hd[5][2];
        #pragma unroll
        for (int d = 0; d < 5; ++d) {
            const float bp = b_proj[i * 5 + d];
            const float4* wp = (const float4*)(W_proj + (size_t)i * 5120 + (size_t)d * 1024);
            float a0 = 0.f, a1 = 0.f;
            #pragma unroll
            for (int j = 0; j < 4; ++j) {
                const float4 w = wp[lane + 64 * j];   // L1/L2-hot, same lines all waves
                a0 = fmaf(w.x, r4[0][j].x, a0); a0 = fmaf(w.y, r4[0][j].y, a0);
                a0 = fmaf(w.z, r4[0][j].z, a0); a0 = fmaf(w.w, r4[0][j].w, a0);
                a1 = fmaf(w.x, r4[1][j].x, a1); a1 = fmaf(w.y, r4[1][j].y, a1);
                a1 = fmaf(w.z, r4[1][j].z, a1); a1 = fmaf(w.w, r4[1][j].w, a1);
            }
            float av[2] = {a0, a1};
            #pragma unroll
            for (int rr = 0; rr < 2; ++rr) {
                float v = av[rr];
                v += __shfl_xor(v, 1);
                v += __shfl_xor(v, 2);
                v += __shfl_xor(v, 4);
                v += __shfl_xor(v, 8);
                v += __shfl_xor(v, 16);
                v += __shfl_xor(v, 32);
                hd[d][rr] = v + bp;
            }
        }

        // ---- bound + gumbel-argmax (bit-identical math/order) ----
        float zq_mine[2];
        #pragma unroll
        for (int rr = 0; rr < 2; ++rr) {
            float hsel = hd[0][rr];
            hsel = (dl == 1) ? hd[1][rr] : hsel;
            hsel = (dl == 2) ? hd[2][rr] : hsel;
            hsel = (dl == 3) ? hd[3][rr] : hsel;
            hsel = (dl == 4) ? hd[4][rr] : hsel;
            const float z  = __fsub_rn(__fmul_rn(tanhf(hsel + shiftd), halfld), offd);
            const float g1 = logf(uu[i][rr] + 1e-20f);
            const float g  = -logf(-g1 + 1e-20f);
            const float df = __fsub_rn(z, stepf);
            float d2 = __fmul_rn(df, df);
            d2 = valid ? d2 : 1e8f;
            const float d2x = fmaf(alpham1, d2, d2);
            float y   = -(d2x * inv_te) + g;
            int   idx = cl;
            #pragma unroll
            for (int m = 1; m <= 4; m <<= 1) {     // argmax in 8-lane group
                const float yo = __shfl_xor(y, m);
                const int   io = __shfl_xor(idx, m);
                const bool take = (yo > y) || (yo == y && io < idx);
                y   = take ? yo : y;
                idx = take ? io : idx;
            }
            zq_mine[rr] = (float)(idx - 4) * invhwd;
        }
        if (lane < 40 && cl == 0) {
            #pragma unroll
            for (int rr = 0; rr < 2; ++rr)
                out_code[(size_t)(row0 + rr) * 20 + i * 5 + dl] = zq_mine[rr];
        }

        // broadcast zq[d][rr] into SGPRs (readlane, imm lane) — no VGPR cost
        float zq[5][2];
        #pragma unroll
        for (int d = 0; d < 5; ++d)
            #pragma unroll
            for (int rr = 0; rr < 2; ++rr)
                zq[d][rr] = __int_as_float(
                    __builtin_amdgcn_readlane(__float_as_int(zq_mine[rr]), d * 8));

        __syncthreads();   // B: sWi writes (long done, hidden by proj) visible

        // ---- inverse proj fused into r update (identical rounding order):
        //      t = b_inv + zq0*w0 + ... + zq4*w4 ; r -= t ----
        #pragma unroll
        for (int j = 0; j < 4; ++j) {
            const int eo = 4 * lane + 256 * j;
            const float4 b  = bv[j];
            const float4 w0 = *(const float4*)&sWi[eo];
            const float4 w1 = *(const float4*)&sWi[1024 + eo];
            const float4 w2 = *(const float4*)&sWi[2048 + eo];
            const float4 w3 = *(const float4*)&sWi[3072 + eo];
            const float4 w4 = *(const float4*)&sWi[4096 + eo];
            #pragma unroll
            for (int rr = 0; rr < 2; ++rr) {
                float tx = b.x, ty = b.y, tz = b.z, tw = b.w;
                tx = fmaf(zq[0][rr], w0.x, tx); ty = fmaf(zq[0][rr], w0.y, ty);
                tz = fmaf(zq[0][rr], w0.z, tz); tw = fmaf(zq[0][rr], w0.w, tw);
                tx = fmaf(zq[1][rr], w1.x, tx); ty = fmaf(zq[1][rr], w1.y, ty);
                tz = fmaf(zq[1][rr], w1.z, tz); tw = fmaf(zq[1][rr], w1.w, tw);
                tx = fmaf(zq[2][rr], w2.x, tx); ty = fmaf(zq[2][rr], w2.y, ty);
                tz = fmaf(zq[2][rr], w2.z, tz); tw = fmaf(zq[2][rr], w2.w, tw);
                tx = fmaf(zq[3][rr], w3.x, tx); ty = fmaf(zq[3][rr], w3.y, ty);
                tz = fmaf(zq[3][rr], w3.z, tz); tw = fmaf(zq[3][rr], w3.w, tw);
                tx = fmaf(zq[4][rr], w4.x, tx); ty = fmaf(zq[4][rr], w4.y, ty);
                tz = fmaf(zq[4][rr], w4.z, tz); tw = fmaf(zq[4][rr], w4.w, tw);
                r4[rr][j].x -= tx; r4[rr][j].y -= ty;
                r4[rr][j].z -= tz; r4[rr][j].w -= tw;
            }
        }

        // ---- loss snapshot: ||r||^2 at the selected stage ----
        const float lo = i * 0.25f, hi = (i + 1) * 0.25f;
        #pragma unroll
        for (int rr = 0; rr < 2; ++rr) {
            if (lo < p_r[rr] && p_r[rr] <= hi) {
                float s = 0.f;
                #pragma unroll
                for (int j = 0; j < 4; ++j) {
                    s = fmaf(r4[rr][j].x, r4[rr][j].x, s);
                    s = fmaf(r4[rr][j].y, r4[rr][j].y, s);
                    s = fmaf(r4[rr][j].z, r4[rr][j].z, s);
                    s = fmaf(r4[rr][j].w, r4[rr][j].w, s);
                }
                ss[rr] = s;
            }
        }
    }

    // ---- epilogue: out_q = h_in - r_final; loss reduce ----
    float lsum = 0.f;
    #pragma unroll
    for (int rr = 0; rr < 2; ++rr) {
        float v = ss[rr];
        v += __shfl_xor(v, 1);
        v += __shfl_xor(v, 2);
        v += __shfl_xor(v, 4);
        v += __shfl_xor(v, 8);
        v += __shfl_xor(v, 16);
        v += __shfl_xor(v, 32);
        lsum += sqrtf(v);
    }
    #pragma unroll
    for (int rr = 0; rr < 2; ++rr) {
        const float4* src = (const float4*)(h_in + (size_t)(row0 + rr) * EDIM);
        float4* dst = (float4*)(out_q + (size_t)(row0 + rr) * EDIM);
        #pragma unroll
        for (int j = 0; j < 4; ++j) {
            const float4 h = src[lane + 64 * j];
            float4 o;
            o.x = h.x - r4[rr][j].x;
            o.y = h.y - r4[rr][j].y;
            o.z = h.z - r4[rr][j].z;
            o.w = h.w - r4[rr][j].w;
            dst[lane + 64 * j] = o;
        }
    }
    if (lane == 0) sLoss[wib] = lsum;
    __syncthreads();
    if (tid == 0) {
        const float bl = (sLoss[0] + sLoss[1]) + (sLoss[2] + sLoss[3]);
        atomicAdd(out_loss, bl * (1.0f / 65536.0f));
    }
}

extern "C" void kernel_launch(void* const* d_in, const int* in_sizes, int n_in,
                              void* d_out, int out_size, void* d_ws, size_t ws_size,
                              hipStream_t stream) {
    (void)in_sizes; (void)n_in; (void)out_size; (void)ws_size;
    const float* h_in   = (const float*)d_in[0];
    const float* W_proj = (const float*)d_in[1];
    const float* b_proj = (const float*)d_in[2];
    const float* W_inv  = (const float*)d_in[3];
    const float* b_inv  = (const float*)d_in[4];
    const float* temp   = (const float*)d_in[5];
    const float* u      = (const float*)d_in[6];
    const float* p      = (const float*)d_in[7];

    float* out_q    = (float*)d_out;
    float* out_code = out_q + (size_t)NROWS * EDIM;
    float* out_loss = out_code + (size_t)NROWS * 20;

    float* WiT = (float*)d_ws;   // 4*5*1024 floats = 80 KB scratch

    // loss accumulator must start at 0 (d_out is poisoned before every call)
    hipMemsetAsync(out_loss, 0, sizeof(float), stream);

    // transpose W_inv once per call (80 KB, ~2 us)
    hipLaunchKernelGGL(winv_transpose, dim3(16), dim3(256), 0, stream, W_inv, WiT);

    // shift constants computed exactly as numpy does (f64 then cast)
    double hl01 = (8.0 - 1.0) * (1.0 - 1e-3) / 2.0;   // 3.4965
    double hl3  = (6.0 - 1.0) * (1.0 - 1e-3) / 2.0;   // 2.4975
    float shift012 = (float)std::tan(0.5 / hl01);
    float shift3   = (float)std::tan(0.5 / hl3);

    dim3 grid(NROWS / 8);   // 4 waves/block * 2 rows/wave
    dim3 block(256);
    hipLaunchKernelGGL(rvq_fused, grid, block, 0, stream,
                       h_in, W_proj, b_proj, WiT, b_inv, temp, u, p,
                       out_q, out_code, out_loss, shift012, shift3);
}